// Round 7
// baseline (116.966 us; speedup 1.0000x reference)
//
#include <hip/hip_runtime.h>

// DTW loss: sum |preds[b, path_i[b,p]] - targets[b, path_j[b,p]]|_1 / (B*S)
// B=256, S=8192, P=16383. preds/targets fp32 (B,S,2); path_* int32 (B,P).
//
// R6 = MEASUREMENT ROUND (pre-committed in R5). The main kernel is invisible
// in rocprof top-5 (harness's 268 MB poison fills own every slot); cross-round
// subtraction gives K~33 us but the model says ~16 us. Run the IDENTICAL main
// kernel TWICE (second pass -> partial[256..511]; final sums 512 and scales by
// 0.5/(B*S), exact: (T+T)*0.5 == T in fp32). K = dur_us(R6) - dur_us(R5).
// K>=25us -> kernel genuinely slow, attack phase structure. K<=18us -> harness
// overhead dominates; revert to single pass and declare roofline.

#define BB 256
#define SS 8192
#define PP 16383
#define NT 1024
#define NIT 16           // ceil(PP / NT): 15 full iters + 1 guarded

__global__ __launch_bounds__(NT, 4) void dtw_loss_kernel(
    const float* __restrict__ preds,
    const float* __restrict__ targets,
    const int* __restrict__ path_i,
    const int* __restrict__ path_j,
    float* __restrict__ partial)   // 256 slots per pass; no init needed
{
    // 128 KB: preds window fp32 float2 in [0, 2*SS) floats, targets after.
    __shared__ float lds[4 * SS];
    __shared__ float wred[16];

    const int tid   = threadIdx.x;
    const int batch = blockIdx.x;          // one block per batch
    const int wave  = tid >> 6;            // 0..15
    const int lane  = tid & 63;

    const char* pbase = (const char*)(preds   + (size_t)batch * SS * 2);  // 64 KB
    const char* tbase = (const char*)(targets + (size_t)batch * SS * 2);  // 64 KB
    const int* __restrict__ pi = path_i + (size_t)batch * PP;
    const int* __restrict__ pj = path_j + (size_t)batch * PP;

    // --- stage both 64 KB fp32 windows via direct global->LDS DMA ---
    #pragma unroll
    for (int u = 0; u < 4; ++u) {
        const int off = (wave * 4 + u) * 1024;          // byte offset in window
        __builtin_amdgcn_global_load_lds(
            (const __attribute__((address_space(1))) void*)(pbase + off + lane * 16),
            (__attribute__((address_space(3))) void*)((char*)lds + off),
            16, 0, 0);
        __builtin_amdgcn_global_load_lds(
            (const __attribute__((address_space(1))) void*)(tbase + off + lane * 16),
            (__attribute__((address_space(3))) void*)((char*)lds + 65536 + off),
            16, 0, 0);
    }

    // --- prefetch ALL indices (packed 16+16; S=8192 < 2^16), pinned in VGPRs
    unsigned pk[NIT];
    #pragma unroll
    for (int u = 0; u < NIT; ++u) {
        int k = u * NT + tid;
        if (u == NIT - 1) k = min(k, PP - 1);
        pk[u] = ((unsigned)pi[k]) | ((unsigned)pj[k] << 16);
    }
    #pragma unroll
    for (int u = 0; u < NIT; ++u)
        asm volatile("" : "+v"(pk[u]));

    __syncthreads();   // drains vmcnt(0): all DMA deposits + index loads done

    // --- gather from LDS: 32 independent ds_read_b64 per thread ---
    const float2* __restrict__ lp = (const float2*)lds;            // preds
    const float2* __restrict__ lt = (const float2*)(lds + 2 * SS); // targets
    float acc = 0.0f;
    #pragma unroll
    for (int u = 0; u < NIT; ++u) {
        const unsigned i = pk[u] & 0xffffu;
        const unsigned j = pk[u] >> 16;
        const float2 a = lp[i];
        const float2 b = lt[j];
        const float d = fabsf(a.x - b.x) + fabsf(a.y - b.y);
        if (u < NIT - 1 || u * NT + tid < PP) acc += d;   // tail: 1023 valid
    }

    // --- wave reduce -> block reduce -> ONE plain store per block ---
    #pragma unroll
    for (int off = 32; off > 0; off >>= 1)
        acc += __shfl_down(acc, off, 64);
    if (lane == 0) wred[wave] = acc;
    __syncthreads();
    if (tid < 16) {
        float s = wred[tid];
        s += __shfl_down(s, 8, 64);
        s += __shfl_down(s, 4, 64);
        s += __shfl_down(s, 2, 64);
        s += __shfl_down(s, 1, 64);
        if (tid == 0) partial[batch] = s;   // unique slot: no atomic, no init
    }
}

__global__ __launch_bounds__(128) void dtw_final_kernel(
    const float* __restrict__ partial, float* __restrict__ out)
{
    // 512 partials (two passes) = 128 lanes x float4.
    const float4 v = ((const float4*)partial)[threadIdx.x];
    float s = (v.x + v.y) + (v.z + v.w);
    #pragma unroll
    for (int off = 32; off > 0; off >>= 1)
        s += __shfl_down(s, off, 64);
    __shared__ float w2[2];
    if ((threadIdx.x & 63) == 0) w2[threadIdx.x >> 6] = s;
    __syncthreads();
    if (threadIdx.x == 0)
        out[0] = (w2[0] + w2[1]) * (0.5f / ((float)BB * (float)SS));
}

extern "C" void kernel_launch(void* const* d_in, const int* in_sizes, int n_in,
                              void* d_out, int out_size, void* d_ws, size_t ws_size,
                              hipStream_t stream) {
    const float* preds   = (const float*)d_in[0];
    const float* targets = (const float*)d_in[1];
    const int*   path_i  = (const int*)d_in[2];
    const int*   path_j  = (const int*)d_in[3];
    float* partial = (float*)d_ws;    // 512 floats; every slot written each call
    float* out     = (float*)d_out;

    // Pass 1 and pass 2: identical work, disjoint output slots.
    dtw_loss_kernel<<<BB, NT, 0, stream>>>(preds, targets, path_i, path_j, partial);
    dtw_loss_kernel<<<BB, NT, 0, stream>>>(preds, targets, path_i, path_j, partial + BB);
    dtw_final_kernel<<<1, 128, 0, stream>>>(partial, out);
}

// Round 8
// 98.642 us; speedup vs baseline: 1.1858x; 1.1858x over previous
//
#include <hip/hip_runtime.h>

// DTW loss: sum |preds[b, path_i[b,p]] - targets[b, path_j[b,p]]|_1 / (B*S)
// B=256, S=8192, P=16383. preds/targets fp32 (B,S,2); path_* int32 (B,P).
//
// R6 measurement (two identical passes): K = 116.97 - 102.83 = 14.1 us for
// one full pass of the main kernel -> the kernel is at ~14-16 us vs the
// 10.6 us streaming floor; the other ~88 us of the bench is harness-fixed
// (268 MB ws poison fills ~42 us each own the rocprof top-5). R3-R5's
// "K~33us" was a stale-overhead subtraction artifact. This round: revert to
// the single-pass R5 kernel (the measurement duplicate must not ship).
//
// Final structure: one block per batch stages both 64 KB fp32 windows via
// global->LDS DMA (width-16) while index loads stream concurrently (packed
// 16+16, asm-pinned so they can't sink past the barrier); random ds_read_b64
// gathers from 128 KB LDS; block reduce -> one plain store per block; tiny
// final kernel reduces 256 partials. No atomics, no memset node.

#define BB 256
#define SS 8192
#define PP 16383
#define NT 1024
#define NIT 16           // ceil(PP / NT): 15 full iters + 1 guarded

__global__ __launch_bounds__(NT, 4) void dtw_loss_kernel(
    const float* __restrict__ preds,
    const float* __restrict__ targets,
    const int* __restrict__ path_i,
    const int* __restrict__ path_j,
    float* __restrict__ partial)   // 256 slots, one per block; no init needed
{
    // 128 KB: preds window fp32 float2 in [0, 2*SS) floats, targets after.
    __shared__ float lds[4 * SS];
    __shared__ float wred[16];

    const int tid   = threadIdx.x;
    const int batch = blockIdx.x;          // one block per batch
    const int wave  = tid >> 6;            // 0..15
    const int lane  = tid & 63;

    const char* pbase = (const char*)(preds   + (size_t)batch * SS * 2);  // 64 KB
    const char* tbase = (const char*)(targets + (size_t)batch * SS * 2);  // 64 KB
    const int* __restrict__ pi = path_i + (size_t)batch * PP;
    const int* __restrict__ pj = path_j + (size_t)batch * PP;

    // --- stage both 64 KB fp32 windows via direct global->LDS DMA ---
    // Each wave: 4 x 1 KB instrs per array; HW deposits at lds_base + lane*16.
    #pragma unroll
    for (int u = 0; u < 4; ++u) {
        const int off = (wave * 4 + u) * 1024;          // byte offset in window
        __builtin_amdgcn_global_load_lds(
            (const __attribute__((address_space(1))) void*)(pbase + off + lane * 16),
            (__attribute__((address_space(3))) void*)((char*)lds + off),
            16, 0, 0);
        __builtin_amdgcn_global_load_lds(
            (const __attribute__((address_space(1))) void*)(tbase + off + lane * 16),
            (__attribute__((address_space(3))) void*)((char*)lds + 65536 + off),
            16, 0, 0);
    }

    // --- prefetch ALL indices (packed 16+16; S=8192 < 2^16), pinned in VGPRs
    // so the loads cannot sink past the barrier (R2 failure mode).
    unsigned pk[NIT];
    #pragma unroll
    for (int u = 0; u < NIT; ++u) {
        int k = u * NT + tid;
        if (u == NIT - 1) k = min(k, PP - 1);
        pk[u] = ((unsigned)pi[k]) | ((unsigned)pj[k] << 16);
    }
    #pragma unroll
    for (int u = 0; u < NIT; ++u)
        asm volatile("" : "+v"(pk[u]));

    __syncthreads();   // drains vmcnt(0): all DMA deposits + index loads done

    // --- gather from LDS: 32 independent ds_read_b64 per thread ---
    const float2* __restrict__ lp = (const float2*)lds;            // preds
    const float2* __restrict__ lt = (const float2*)(lds + 2 * SS); // targets
    float acc = 0.0f;
    #pragma unroll
    for (int u = 0; u < NIT; ++u) {
        const unsigned i = pk[u] & 0xffffu;
        const unsigned j = pk[u] >> 16;
        const float2 a = lp[i];
        const float2 b = lt[j];
        const float d = fabsf(a.x - b.x) + fabsf(a.y - b.y);
        if (u < NIT - 1 || u * NT + tid < PP) acc += d;   // tail: 1023 valid
    }

    // --- wave reduce -> block reduce -> ONE plain store per block ---
    #pragma unroll
    for (int off = 32; off > 0; off >>= 1)
        acc += __shfl_down(acc, off, 64);
    if (lane == 0) wred[wave] = acc;
    __syncthreads();
    if (tid < 16) {
        float s = wred[tid];
        s += __shfl_down(s, 8, 64);
        s += __shfl_down(s, 4, 64);
        s += __shfl_down(s, 2, 64);
        s += __shfl_down(s, 1, 64);
        if (tid == 0) partial[batch] = s;   // unique slot: no atomic, no init
    }
}

__global__ __launch_bounds__(64) void dtw_final_kernel(
    const float* __restrict__ partial, float* __restrict__ out)
{
    // 256 partials = 64 lanes x float4; kernel boundary guarantees visibility.
    const float4 v = ((const float4*)partial)[threadIdx.x];
    float s = (v.x + v.y) + (v.z + v.w);
    #pragma unroll
    for (int off = 32; off > 0; off >>= 1)
        s += __shfl_down(s, off, 64);
    if (threadIdx.x == 0)
        out[0] = s * (1.0f / ((float)BB * (float)SS));   // *2^-21, exact scale
}

extern "C" void kernel_launch(void* const* d_in, const int* in_sizes, int n_in,
                              void* d_out, int out_size, void* d_ws, size_t ws_size,
                              hipStream_t stream) {
    const float* preds   = (const float*)d_in[0];
    const float* targets = (const float*)d_in[1];
    const int*   path_i  = (const int*)d_in[2];
    const int*   path_j  = (const int*)d_in[3];
    float* partial = (float*)d_ws;    // 256 floats; every slot written each call
    float* out     = (float*)d_out;

    dtw_loss_kernel<<<BB, NT, 0, stream>>>(preds, targets, path_i, path_j, partial);
    dtw_final_kernel<<<1, 64, 0, stream>>>(partial, out);
}